// Round 8
// baseline (45.761 us; speedup 1.0000x reference)
//
#include <hip/hip_runtime.h>
#include <math.h>

#define BDIM 4096
#define DDIM 128
#define EPSF 1e-12f
#define TI 128
#define TJc 128
#define NSPLIT 16
#define NSLICE (NSPLIT * 2)                 // 32: one slice per 64-col half
#define ITILES (BDIM / TI)                  // 32
#define JT 6                                // (3*4096/128)/NSPLIT
#define FLT_BIG 3.402823466e+38f
#define MATSZ (BDIM * DDIM)                 // 524288

typedef __attribute__((ext_vector_type(8))) _Float16 f16x8;
typedef __attribute__((ext_vector_type(16))) float f32x16;

__device__ __forceinline__ unsigned int pack2h(float x, float y) {
    _Float16 hx = (_Float16)x, hy = (_Float16)y;
    unsigned short ux, uy;
    __builtin_memcpy(&ux, &hx, 2);
    __builtin_memcpy(&uy, &hy, 2);
    return (unsigned int)ux | ((unsigned int)uy << 16);
}

// ---------------- Kernel 0: fused fp16 convert + row norms + distance_pos ----
__global__ __launch_bounds__(256) void prep_kernel(
    const float* __restrict__ A, const float* __restrict__ P,
    const float* __restrict__ N, ushort* __restrict__ Xf,
    float* __restrict__ a2, float* __restrict__ p2,
    float* __restrict__ n2, float* __restrict__ dpos) {
    int row = (blockIdx.x * blockDim.x + threadIdx.x) >> 6;
    int lane = threadIdx.x & 63;
    if (row >= BDIM) return;
    const float2 av = *(const float2*)&A[row * DDIM + lane * 2];
    const float2 pv = *(const float2*)&P[row * DDIM + lane * 2];
    const float2 nv = *(const float2*)&N[row * DDIM + lane * 2];
    *(unsigned int*)&Xf[0 * MATSZ + row * DDIM + lane * 2] = pack2h(av.x, av.y);
    *(unsigned int*)&Xf[1 * MATSZ + row * DDIM + lane * 2] = pack2h(pv.x, pv.y);
    *(unsigned int*)&Xf[2 * MATSZ + row * DDIM + lane * 2] = pack2h(nv.x, nv.y);
    float sa = av.x * av.x + av.y * av.y;
    float sp = pv.x * pv.x + pv.y * pv.y;
    float sn = nv.x * nv.x + nv.y * nv.y;
    float dx = av.x - pv.x, dy = av.y - pv.y;
    float sd = dx * dx + dy * dy;
    #pragma unroll
    for (int off = 32; off; off >>= 1) {
        sa += __shfl_down(sa, off);
        sp += __shfl_down(sp, off);
        sn += __shfl_down(sn, off);
        sd += __shfl_down(sd, off);
    }
    if (lane == 0) {
        a2[row] = sa;
        p2[row] = sp;
        n2[row] = sn;
        dpos[row] = sqrtf(fmaxf(sd, EPSF));
    }
}

// ---------------- Kernel 1: fp16 MFMA min of (y2/2 - dot), NO LDS ----------
// Xf (3 MB) is L2-resident: B fragments are read straight from global in the
// native MFMA layout (1 KB/instr coalesced). No LDS, no barriers — waves
// free-run; next tile's loads overlap current tile's MFMAs.
// grid (32 i-tiles, 16 splits), 256 thr = 4 waves; wave = 64 rows x 64 cols.
__global__ __launch_bounds__(256, 2) void minsq_kernel(
    const ushort* __restrict__ Xf,
    const float* __restrict__ a2, const float* __restrict__ p2,
    const float* __restrict__ n2, float* __restrict__ partial) {
    const int tid = threadIdx.x;
    const int w = tid >> 6;
    const int lane = tid & 63;
    const int rg = w >> 1;    // 64-row group of the 128-row i-tile
    const int ch = w & 1;     // 64-col half of the 128-col j-tile
    const int iTile = blockIdx.x;
    const int split = blockIdx.y;
    const int i0 = iTile * TI;
    const int jt0 = split * JT;

    // A fragments direct from global (L2-resident; prologue only)
    f16x8 a0[8], a1[8];
    {
        const ushort* r0 =
            Xf + (size_t)(i0 + rg * 64 + (lane & 31)) * DDIM + (lane >> 5) * 8;
        const ushort* r1 = r0 + 32 * DDIM;
        #pragma unroll
        for (int t = 0; t < 8; ++t) {
            a0[t] = *(const f16x8*)(r0 + t * 16);
            a1[t] = *(const f16x8*)(r1 + t * 16);
        }
    }
    // y2/2 per tile and col-block
    float y2h0[JT], y2h1[JT];
    #pragma unroll
    for (int t = 0; t < JT; ++t) {
        int jt = jt0 + t, m = jt >> 5, tc = jt & 31;
        const float* y2g = (m == 0) ? a2 : ((m == 1) ? p2 : n2);
        int jb = tc * TJc + ch * 64 + (lane & 31);
        y2h0[t] = 0.5f * y2g[jb];
        y2h1[t] = 0.5f * y2g[jb + 32];
    }

    float minv0[16], minv1[16];
    #pragma unroll
    for (int g = 0; g < 16; ++g) { minv0[g] = FLT_BIG; minv1[g] = FLT_BIG; }

    #pragma unroll
    for (int idx = 0; idx < JT; ++idx) {
        const int jt = jt0 + idx;
        const int m = jt >> 5;
        const int tc = jt & 31;
        // B fragment base: row = tc*128 + ch*64 + (lane&31), slot (lane>>5)
        const ushort* pb0 = Xf + (size_t)m * MATSZ +
                            (size_t)(tc * TJc + ch * 64 + (lane & 31)) * DDIM +
                            (lane >> 5) * 8;
        const ushort* pb1 = pb0 + 32 * DDIM;

        f32x16 acc00 = {}, acc01 = {}, acc10 = {}, acc11 = {};
        // two half-passes of 4 k-slices: limits live B regs to 32 VGPR
        #pragma unroll
        for (int half = 0; half < 2; ++half) {
            f16x8 b0[4], b1[4];
            #pragma unroll
            for (int q = 0; q < 4; ++q) {
                int t = half * 4 + q;
                b0[q] = *(const f16x8*)(pb0 + t * 16);
                b1[q] = *(const f16x8*)(pb1 + t * 16);
            }
            __builtin_amdgcn_s_setprio(1);
            #pragma unroll
            for (int q = 0; q < 4; ++q) {
                int t = half * 4 + q;
                acc00 = __builtin_amdgcn_mfma_f32_32x32x16_f16(a0[t], b0[q], acc00, 0, 0, 0);
                acc10 = __builtin_amdgcn_mfma_f32_32x32x16_f16(a1[t], b0[q], acc10, 0, 0, 0);
                acc01 = __builtin_amdgcn_mfma_f32_32x32x16_f16(a0[t], b1[q], acc01, 0, 0, 0);
                acc11 = __builtin_amdgcn_mfma_f32_32x32x16_f16(a1[t], b1[q], acc11, 0, 0, 0);
            }
            __builtin_amdgcn_s_setprio(0);
        }

        // epilogue: running min of (y2/2 - dot); diag exclusion on A/P mats
        {
            float yh0 = y2h0[idx], yh1 = y2h1[idx];
            if (m < 2 && tc == iTile) {
                int jg0 = tc * TJc + ch * 64 + (lane & 31);
                int jg1 = jg0 + 32;
                #pragma unroll
                for (int g = 0; g < 16; ++g) {
                    int rloc = (g & 3) + 8 * (g >> 2) + 4 * (lane >> 5);
                    int ig0 = i0 + rg * 64 + rloc;
                    int ig1 = ig0 + 32;
                    float c;
                    c = yh0 - acc00[g]; if (ig0 == jg0) c = FLT_BIG;
                    minv0[g] = fminf(minv0[g], c);
                    c = yh1 - acc01[g]; if (ig0 == jg1) c = FLT_BIG;
                    minv0[g] = fminf(minv0[g], c);
                    c = yh0 - acc10[g]; if (ig1 == jg0) c = FLT_BIG;
                    minv1[g] = fminf(minv1[g], c);
                    c = yh1 - acc11[g]; if (ig1 == jg1) c = FLT_BIG;
                    minv1[g] = fminf(minv1[g], c);
                }
            } else {
                #pragma unroll
                for (int g = 0; g < 16; ++g) {
                    minv0[g] = fminf(minv0[g], fminf(yh0 - acc00[g], yh1 - acc01[g]));
                    minv1[g] = fminf(minv1[g], fminf(yh0 - acc10[g], yh1 - acc11[g]));
                }
            }
        }
    }

    // min over the 32 columns of each col-block (within 32-lane halves)
    #pragma unroll
    for (int off = 1; off < 32; off <<= 1) {
        #pragma unroll
        for (int g = 0; g < 16; ++g) {
            minv0[g] = fminf(minv0[g], __shfl_xor(minv0[g], off));
            minv1[g] = fminf(minv1[g], __shfl_xor(minv1[g], off));
        }
    }
    if ((lane & 31) == 0) {
        int hi = lane >> 5;
        int slice = split * 2 + ch;
        #pragma unroll
        for (int g = 0; g < 16; ++g) {
            int rloc = (g & 3) + 8 * (g >> 2) + 4 * hi;
            int ig = i0 + rg * 64 + rloc;
            partial[(size_t)ig * NSLICE + slice] = minv0[g];
            partial[(size_t)(ig + 32) * NSLICE + slice] = minv1[g];
        }
    }
}

// ---------------- Kernel 2a: per-row loss, 16-block partial sums ------------
__global__ __launch_bounds__(256) void lossA_kernel(
    const float* __restrict__ partial, const float* __restrict__ a2,
    const float* __restrict__ dpos, float* __restrict__ bsum) {
    __shared__ float red[4];
    int i = blockIdx.x * 256 + threadIdx.x;
    const float4* pr = (const float4*)&partial[(size_t)i * NSLICE];
    float mv = FLT_BIG;
    #pragma unroll
    for (int q = 0; q < NSLICE / 4; ++q) {
        float4 v = pr[q];
        mv = fminf(mv, fminf(fminf(v.x, v.y), fminf(v.z, v.w)));
    }
    float h2 = a2[i] + 2.0f * mv;
    float hardest = sqrtf(fmaxf(h2, EPSF));
    float x = dpos[i] - hardest;
    float sum = fmaxf(x, 0.f) + log1pf(expf(-fabsf(x)));
    #pragma unroll
    for (int off = 32; off; off >>= 1) sum += __shfl_down(sum, off);
    if ((threadIdx.x & 63) == 0) red[threadIdx.x >> 6] = sum;
    __syncthreads();
    if (threadIdx.x == 0)
        bsum[blockIdx.x] = red[0] + red[1] + red[2] + red[3];
}

// ---------------- Kernel 2b: final scalar ----------------
__global__ void lossB_kernel(const float* __restrict__ bsum,
                             float* __restrict__ out) {
    float v = (threadIdx.x < 16) ? bsum[threadIdx.x] : 0.f;
    #pragma unroll
    for (int off = 32; off; off >>= 1) v += __shfl_down(v, off);
    if (threadIdx.x == 0) out[0] = v * (1.0f / BDIM);
}

extern "C" void kernel_launch(void* const* d_in, const int* in_sizes, int n_in,
                              void* d_out, int out_size, void* d_ws, size_t ws_size,
                              hipStream_t stream) {
    const float* A = (const float*)d_in[0];
    const float* P = (const float*)d_in[1];
    const float* N = (const float*)d_in[2];

    float* ws = (float*)d_ws;
    float* a2 = ws;                          // 4096
    float* p2 = ws + BDIM;                   // 4096
    float* n2 = ws + 2 * BDIM;               // 4096
    float* dpos = ws + 3 * BDIM;             // 4096
    float* bsum = ws + 4 * BDIM;             // 64 (16 used)
    float* partial = ws + 4 * BDIM + 64;     // BDIM * NSLICE (row-major)
    ushort* Xf = (ushort*)(partial + (size_t)BDIM * NSLICE);  // 3*524288 fp16

    prep_kernel<<<BDIM / 4, 256, 0, stream>>>(A, P, N, Xf, a2, p2, n2, dpos);
    dim3 grid2(ITILES, NSPLIT);
    minsq_kernel<<<grid2, 256, 0, stream>>>(Xf, a2, p2, n2, partial);
    lossA_kernel<<<16, 256, 0, stream>>>(partial, a2, dpos, bsum);
    lossB_kernel<<<1, 64, 0, stream>>>(bsum, (float*)d_out);
}